// Round 10
// baseline (51.845 us; speedup 1.0000x reference)
//
#include <hip/hip_runtime.h>
#include <hip/hip_bf16.h>
#include <math.h>

typedef __bf16 bf16;
typedef __attribute__((ext_vector_type(4))) float f32x4;
typedef __attribute__((ext_vector_type(8))) bf16 bf16x8;

#define M_TOT 16384
#define K_TOT 1024
#define D_EMB 512
#define NT 32          // K tiles of 32

// ============================================================
// Pass 0 (unchanged from r9, verified): W -> fragment-ordered bf16
// image (2 MB). Blob (estrip, kt) = 1 KB:
//   img[((es*32+kt)*64 + lane)*8 + j]
//     = W_cat[es*16 + (lane&15)][kt*32 + (lane>>4)*8 + j]
// ============================================================
__global__ __launch_bounds__(256) void cvt_w_img(
    const float* __restrict__ W_mu, const float* __restrict__ W_logvar,
    bf16* __restrict__ img)
{
    const int c  = blockIdx.x * 256 + threadIdx.x;   // 0..131071
    const int l  = c & 63;
    const int kt = (c >> 6) & 31;
    const int es = c >> 11;                          // 0..63
    const int col = es * 16 + (l & 15);
    const int k0  = kt * 32 + (l >> 4) * 8;
    const float* s = (col < D_EMB) ? (W_mu + (size_t)col * K_TOT + k0)
                                   : (W_logvar + (size_t)(col - D_EMB) * K_TOT + k0);
    f32x4 a = ((const f32x4*)s)[0];
    f32x4 b = ((const f32x4*)s)[1];
    bf16x8 o;
    o[0] = (bf16)a[0]; o[1] = (bf16)a[1]; o[2] = (bf16)a[2]; o[3] = (bf16)a[3];
    o[4] = (bf16)b[0]; o[5] = (bf16)b[1]; o[6] = (bf16)b[2]; o[7] = (bf16)b[3];
    *(bf16x8*)(img + (size_t)c * 8) = o;
}

// ============================================================
// Main GEMM: 128x256 tile, BK=32, 8 waves (2wr x 4wc), wave-tile
// 64x64 (acc[4][4]). grid 512 -> 2 blocks/CU (the experiment).
// LDS 16 KB: A only, double-buffered 128x32 bf16, r6-verified swizzle
// (chunk ^= (row>>1)&3; write AND read sides). B: regs from frag image
// (single set; reloaded after last MFMA use).
// Ledger (entering tile t: FIFO [A(t+1):2 older, B(t):4]):
//   1. vmcnt(0)            // both >=0.7 tile old; co-resident block fills stall
//   2. [t+1<NT] cwA -> buf p^1 ; [t+2<NT] gloadA(t+2) [2]
//   3. ds_read af[4] from buf p
//   4. lgkm(0); barrier    // write visibility + read retirement
//   5. setprio(1); 16 MFMA (af x bv); setprio(0)
//   6. [t+1<NT] gloadB(t+1) -> bv [4]   (anti-dep after MFMA)
// WAR: buf p^1 writes (step 2, after barrier(t-1)) follow all its
// readers' lgkm(0)-drained reads at tile t-1. Visibility: writer's
// step-4 lgkm(0)+barrier precedes readers at t+1.
// ============================================================
__global__ __launch_bounds__(512, 4) void gpe_gemm(
    const float* __restrict__ x,
    const bf16* __restrict__ wimg,
    const float* __restrict__ b_mu,
    const float* __restrict__ b_logvar,
    float* __restrict__ out)         // [2][16384][512]
{
    __shared__ __align__(16) bf16 Alds[2 * 128 * 32];   // 16 KB

    const int tid  = threadIdx.x;
    const int lane = tid & 63;
    const int wid  = tid >> 6;        // 0..7
    const int wr   = wid >> 2;        // 0..1
    const int wc   = wid & 3;         // 0..3

    // T1: bijective XCD swizzle (512 = 8 XCD x 64); bn inner -> the 4
    // blocks sharing an A-panel sit on one XCD's L2.
    const int bid = blockIdx.x;
    const int swz = (bid & 7) * 64 + (bid >> 3);
    const int bn  = swz & 3;          // 0..3 (E quadrant, 256 cols)
    const int bm  = swz >> 2;         // 0..127

    // ---- A staging: thread owns 8 f32 (quarter-row) ----
    const int r_l = tid >> 2;                         // 0..127
    const int q   = tid & 3;
    const float* __restrict__ Asrc = x + (size_t)(bm * 128 + r_l) * K_TOT + q * 8;
    const int woff = r_l * 32 + ((q ^ ((r_l >> 1) & 3)) << 3);   // elems

    // ---- frag read geometry ----
    const int fr  = lane & 15;
    const int g16 = lane >> 4;

    // ---- B image base: 4 estrips per wave (r9 layout) ----
    const bf16* __restrict__ bb =
        wimg + (size_t)(bn * 16 + wc * 4) * 16384 + lane * 8;

    f32x4 acc[4][4];
#pragma unroll
    for (int m = 0; m < 4; ++m)
#pragma unroll
        for (int n = 0; n < 4; ++n)
            acc[m][n] = (f32x4){0.f, 0.f, 0.f, 0.f};

    f32x4 regA[2];
    bf16x8 bv[4];

    auto gloadA = [&](int t) {
        regA[0] = *(const f32x4*)(Asrc + t * 32);
        regA[1] = *(const f32x4*)(Asrc + t * 32 + 4);
    };
    auto cwA = [&](bf16* abase) {
        bf16x8 w;
#pragma unroll
        for (int j = 0; j < 4; ++j) { w[j] = (bf16)regA[0][j]; w[j + 4] = (bf16)regA[1][j]; }
        *(bf16x8*)&abase[woff] = w;
    };
    auto gloadB = [&](int t) {
#pragma unroll
        for (int n = 0; n < 4; ++n)
            bv[n] = *(const bf16x8*)(bb + (size_t)n * 16384 + t * 512);
    };

    // ---- prologue ----
    gloadA(0);
    asm volatile("s_waitcnt vmcnt(0)" ::: "memory");
    cwA(Alds);                        // buf 0
    gloadA(1);
    gloadB(0);
    asm volatile("s_waitcnt lgkmcnt(0)" ::: "memory");
    __builtin_amdgcn_s_barrier();
    // outstanding: [A1:2, B0:4]

    for (int t = 0; t < NT; ++t) {
        const int p = t & 1;
        bf16* Ab  = Alds + p * 4096;
        bf16* Abn = Alds + (p ^ 1) * 4096;

        asm volatile("s_waitcnt vmcnt(0)" ::: "memory");          // 1
        if (t + 1 < NT) {                                          // 2
            cwA(Abn);
            if (t + 2 < NT) gloadA(t + 2);
        }

        bf16x8 af[4];                                              // 3
#pragma unroll
        for (int m = 0; m < 4; ++m) {
            const int row = wr * 64 + m * 16 + fr;
            af[m] = *(const bf16x8*)&Ab[row * 32 + ((g16 ^ ((row >> 1) & 3)) << 3)];
        }
        asm volatile("s_waitcnt lgkmcnt(0)" ::: "memory");         // 4
        __builtin_amdgcn_s_barrier();

        __builtin_amdgcn_s_setprio(1);                             // 5
#pragma unroll
        for (int n = 0; n < 4; ++n)
#pragma unroll
            for (int m = 0; m < 4; ++m)
                acc[m][n] = __builtin_amdgcn_mfma_f32_16x16x32_bf16(af[m], bv[n], acc[m][n], 0, 0, 0);
        __builtin_amdgcn_s_setprio(0);

        if (t + 1 < NT) gloadB(t + 1);                             // 6
    }

    // ---- epilogue: bias (+ exp for logvar head) ----
    const bool is_mu = (bn < 2);
    const float* __restrict__ bias = is_mu ? b_mu : b_logvar;
    const int cb = (bn & 1) * 256;
    float* __restrict__ obase = is_mu ? out : (out + (size_t)M_TOT * D_EMB);

#pragma unroll
    for (int m = 0; m < 4; ++m) {
        const int row0 = bm * 128 + wr * 64 + m * 16 + g16 * 4;
#pragma unroll
        for (int n = 0; n < 4; ++n) {
            const int c = cb + wc * 64 + n * 16 + fr;
            const float bvs = bias[c];
#pragma unroll
            for (int j = 0; j < 4; ++j) {
                float v = acc[m][n][j] + bvs;
                if (!is_mu) v = __expf(0.5f * v);
                obase[(size_t)(row0 + j) * D_EMB + c] = v;
            }
        }
    }
}

// ============================================================
// Fallback (no workspace): round-1 f32-staging GEMM
// ============================================================
#define LDS_STRIDE 40
__global__ __launch_bounds__(256) void gpe_gemm_fb(
    const float* __restrict__ x, const float* __restrict__ W_mu,
    const float* __restrict__ b_mu, const float* __restrict__ W_logvar,
    const float* __restrict__ b_logvar, float* __restrict__ out)
{
    __shared__ __align__(16) bf16 As[128][LDS_STRIDE];
    __shared__ __align__(16) bf16 Bs[128][LDS_STRIDE];
    typedef __attribute__((ext_vector_type(4))) bf16 bf16x4;
    const int tid = threadIdx.x, lane = tid & 63, wid = tid >> 6;
    const int wr = wid >> 1, wc = wid & 1;
    const int bn = blockIdx.x & 7, bm = blockIdx.x >> 3;
    const int ebase = bn * 128;
    const bool is_mu = (ebase < D_EMB);
    const float* Wp = is_mu ? (W_mu + (size_t)ebase * K_TOT)
                            : (W_logvar + (size_t)(ebase - D_EMB) * K_TOT);
    const float* bias = is_mu ? b_mu : b_logvar;
    const int cbase = is_mu ? ebase : (ebase - D_EMB);
    float* obase = is_mu ? out : (out + (size_t)M_TOT * D_EMB);
    const float* Ap = x + (size_t)(bm * 128) * K_TOT;
    f32x4 acc[4][4];
#pragma unroll
    for (int m = 0; m < 4; ++m)
#pragma unroll
        for (int n = 0; n < 4; ++n) acc[m][n] = (f32x4){0.f, 0.f, 0.f, 0.f};
    const int fr = lane & 15, fk = (lane >> 4) * 8;
    const int arow = wr * 64 + fr, brow = wc * 64 + fr;
    for (int kt = 0; kt < K_TOT / 32; ++kt) {
        const int k0 = kt * 32;
#pragma unroll
        for (int s = 0; s < 4; ++s) {
            const int idx = s * 256 + tid;
            const int row = idx >> 3, col = (idx & 7) << 2;
            f32x4 va = *reinterpret_cast<const f32x4*>(Ap + (size_t)row * K_TOT + k0 + col);
            f32x4 vb = *reinterpret_cast<const f32x4*>(Wp + (size_t)row * K_TOT + k0 + col);
            bf16x4 ha, hb;
#pragma unroll
            for (int j = 0; j < 4; ++j) { ha[j] = (bf16)va[j]; hb[j] = (bf16)vb[j]; }
            *reinterpret_cast<bf16x4*>(&As[row][col]) = ha;
            *reinterpret_cast<bf16x4*>(&Bs[row][col]) = hb;
        }
        __syncthreads();
        bf16x8 af[4], bfv[4];
#pragma unroll
        for (int m = 0; m < 4; ++m)
            af[m] = *reinterpret_cast<const bf16x8*>(&As[arow + m * 16][fk]);
#pragma unroll
        for (int n = 0; n < 4; ++n)
            bfv[n] = *reinterpret_cast<const bf16x8*>(&Bs[brow + n * 16][fk]);
#pragma unroll
        for (int m = 0; m < 4; ++m)
#pragma unroll
            for (int n = 0; n < 4; ++n)
                acc[m][n] = __builtin_amdgcn_mfma_f32_16x16x32_bf16(af[m], bfv[n], acc[m][n], 0, 0, 0);
        __syncthreads();
    }
#pragma unroll
    for (int m = 0; m < 4; ++m) {
        const int rbase = bm * 128 + wr * 64 + m * 16 + (lane >> 4) * 4;
#pragma unroll
        for (int n = 0; n < 4; ++n) {
            const int c = cbase + wc * 64 + n * 16 + (lane & 15);
            const float bv = bias[c];
#pragma unroll
            for (int j = 0; j < 4; ++j) {
                float v = acc[m][n][j] + bv;
                if (!is_mu) v = __expf(0.5f * v);
                obase[(size_t)(rbase + j) * D_EMB + c] = v;
            }
        }
    }
}

extern "C" void kernel_launch(void* const* d_in, const int* in_sizes, int n_in,
                              void* d_out, int out_size, void* d_ws, size_t ws_size,
                              hipStream_t stream) {
    const float* x        = (const float*)d_in[0];
    const float* W_mu     = (const float*)d_in[1];
    const float* b_mu     = (const float*)d_in[2];
    const float* W_logvar = (const float*)d_in[3];
    const float* b_logvar = (const float*)d_in[4];
    float* out = (float*)d_out;

    const size_t ws_needed = (size_t)1024 * 1024 * sizeof(bf16);   // 2 MB W image

    if (ws_size >= ws_needed) {
        bf16* wimg = (bf16*)d_ws;
        cvt_w_img<<<512, 256, 0, stream>>>(W_mu, W_logvar, wimg);
        gpe_gemm<<<512, 512, 0, stream>>>(x, wimg, b_mu, b_logvar, out);
    } else {
        gpe_gemm_fb<<<1024, 256, 0, stream>>>(x, W_mu, b_mu, W_logvar, b_logvar, out);
    }
}